// Round 3
// baseline (353.891 us; speedup 1.0000x reference)
//
#include <hip/hip_runtime.h>

#define NB  8
#define TOQ 2048
#define TIV 2048
#define HD  128

// ---------------------------------------------------------------------------
// K1: E[R][s] = mask ? 0 : exp( dot(Q[row], V[s]) )   (unnormalized, f32)
// 64x64 score tile per block, 256 threads, 4x4 micro-tile per thread.
// Q/V tiles staged TRANSPOSED in LDS ([h][row], pad to 66) so inner-loop
// reads are float2, 2-way-conflict max (free).
// ---------------------------------------------------------------------------
__global__ __launch_bounds__(256) void k1_scores(
    const float* __restrict__ Q, const float* __restrict__ V,
    const int* __restrict__ M, float* __restrict__ E)
{
    __shared__ float qT[HD][66];
    __shared__ float vT[HD][66];

    const int ts = blockIdx.x * 64;   // ti tile base
    const int tt = blockIdx.y * 64;   // to tile base
    const int n  = blockIdx.z;
    const int t  = threadIdx.x;

    const float* Qb = Q + ((size_t)n * TOQ + tt) * HD;
    const float* Vb = V + ((size_t)n * TIV + ts) * HD;

    #pragma unroll
    for (int it = 0; it < 32; ++it) {
        const int i   = t + it * 256;        // 0..8191
        const int row = i >> 7;              // 0..63
        const int h   = i & 127;             // 0..127
        qT[h][row] = Qb[i];
        vT[h][row] = Vb[i];
    }
    __syncthreads();

    const int tm = t >> 4;   // rows 4*tm..4*tm+3
    const int tn = t & 15;   // cols 4*tn..4*tn+3

    float acc[4][4];
    #pragma unroll
    for (int i = 0; i < 4; ++i)
        #pragma unroll
        for (int j = 0; j < 4; ++j) acc[i][j] = 0.f;

    #pragma unroll 4
    for (int h = 0; h < HD; ++h) {
        const float2 a01 = *(const float2*)&qT[h][4 * tm];
        const float2 a23 = *(const float2*)&qT[h][4 * tm + 2];
        const float2 b01 = *(const float2*)&vT[h][4 * tn];
        const float2 b23 = *(const float2*)&vT[h][4 * tn + 2];
        const float a[4] = {a01.x, a01.y, a23.x, a23.y};
        const float b[4] = {b01.x, b01.y, b23.x, b23.y};
        #pragma unroll
        for (int i = 0; i < 4; ++i)
            #pragma unroll
            for (int j = 0; j < 4; ++j)
                acc[i][j] = fmaf(a[i], b[j], acc[i][j]);
    }

    // epilogue: mask (int32 0/1 per element) + exp, store unnormalized e
    #pragma unroll
    for (int i = 0; i < 4; ++i) {
        const size_t R  = (size_t)n * TOQ + tt + 4 * tm + i;   // global row
        const size_t cb = R * TIV + ts + 4 * tn;               // col base
        const int4 mv = *(const int4*)(M + cb);                // mask is int32
        float4 e;
        e.x = mv.x ? 0.f : __expf(acc[i][0]);
        e.y = mv.y ? 0.f : __expf(acc[i][1]);
        e.z = mv.z ? 0.f : __expf(acc[i][2]);
        e.w = mv.w ? 0.f : __expf(acc[i][3]);
        *(float4*)(E + cb) = e;
    }
}

// ---------------------------------------------------------------------------
// K2: rec[row] = 1 / sum_s E[row][s]     (one wave per row)
// ---------------------------------------------------------------------------
__global__ __launch_bounds__(256) void k2_rowsum(
    const float* __restrict__ E, float* __restrict__ rec)
{
    const int row = blockIdx.x * 4 + (threadIdx.x >> 6);
    const int l   = threadIdx.x & 63;
    const float4* Er = (const float4*)(E + (size_t)row * TIV);
    float s = 0.f;
    #pragma unroll
    for (int k = 0; k < 8; ++k) {
        const float4 v = Er[l + 64 * k];
        s += (v.x + v.y) + (v.z + v.w);
    }
    #pragma unroll
    for (int off = 32; off > 0; off >>= 1) s += __shfl_down(s, off, 64);
    if (l == 0) rec[row] = 1.f / s;
}

// ---------------------------------------------------------------------------
// K3: O[row][h] = rec[row] * sum_s E[row][s] * V[s][h]
// ---------------------------------------------------------------------------
__global__ __launch_bounds__(256) void k3_pv(
    const float* __restrict__ E, const float* __restrict__ V,
    const float* __restrict__ rec, float* __restrict__ O)
{
    __shared__ float et[64][68];
    __shared__ float vt[64][132];

    const int n  = blockIdx.y;
    const int r0 = blockIdx.x * 64;
    const int t  = threadIdx.x;
    const int g  = t >> 5;   // rows 8g..8g+7
    const int c  = t & 31;   // float4 column

    const float* Eb = E + ((size_t)n * TOQ + r0) * TIV;
    const float* Vb = V + (size_t)n * TIV * HD;

    float4 acc[8];
    #pragma unroll
    for (int i = 0; i < 8; ++i) acc[i] = make_float4(0.f, 0.f, 0.f, 0.f);

    for (int s0 = 0; s0 < TIV; s0 += 64) {
        #pragma unroll
        for (int it = 0; it < 4; ++it) {             // stage e 64x64
            const int f = t + it * 256;
            const int row = f >> 4, cg = f & 15;
            *(float4*)&et[row][4 * cg] =
                *(const float4*)&Eb[(size_t)row * TIV + s0 + 4 * cg];
        }
        #pragma unroll
        for (int it = 0; it < 8; ++it) {             // stage v 64x128
            const int f = t + it * 256;
            const int sv = f >> 5, hg = f & 31;
            *(float4*)&vt[sv][4 * hg] =
                *(const float4*)&Vb[(size_t)(s0 + sv) * HD + 4 * hg];
        }
        __syncthreads();

        #pragma unroll 2
        for (int s = 0; s < 64; s += 4) {
            const float4 v0 = *(const float4*)&vt[s + 0][4 * c];
            const float4 v1 = *(const float4*)&vt[s + 1][4 * c];
            const float4 v2 = *(const float4*)&vt[s + 2][4 * c];
            const float4 v3 = *(const float4*)&vt[s + 3][4 * c];
            #pragma unroll
            for (int i = 0; i < 8; ++i) {
                const float4 e4 = *(const float4*)&et[8 * g + i][s];
                acc[i].x = fmaf(e4.x, v0.x, fmaf(e4.y, v1.x, fmaf(e4.z, v2.x, fmaf(e4.w, v3.x, acc[i].x))));
                acc[i].y = fmaf(e4.x, v0.y, fmaf(e4.y, v1.y, fmaf(e4.z, v2.y, fmaf(e4.w, v3.y, acc[i].y))));
                acc[i].z = fmaf(e4.x, v0.z, fmaf(e4.y, v1.z, fmaf(e4.z, v2.z, fmaf(e4.w, v3.z, acc[i].z))));
                acc[i].w = fmaf(e4.x, v0.w, fmaf(e4.y, v1.w, fmaf(e4.z, v2.w, fmaf(e4.w, v3.w, acc[i].w))));
            }
        }
        __syncthreads();
    }

    #pragma unroll
    for (int i = 0; i < 8; ++i) {
        const size_t R = (size_t)n * TOQ + r0 + 8 * g + i;
        const float rc = rec[R];
        float4 o;
        o.x = acc[i].x * rc; o.y = acc[i].y * rc;
        o.z = acc[i].z * rc; o.w = acc[i].w * rc;
        *(float4*)(O + R * HD + 4 * c) = o;
    }
}

// ---------------------------------------------------------------------------
// K4: normalize distribution in place: E[row][s] *= rec[row]
// ---------------------------------------------------------------------------
__global__ __launch_bounds__(256) void k4_norm(
    float* __restrict__ E, const float* __restrict__ rec)
{
    const size_t i = (size_t)blockIdx.x * 256 + threadIdx.x;   // float4 index
    float4 v = ((const float4*)E)[i];
    const float rc = rec[i >> 9];   // 512 float4 per row
    v.x *= rc; v.y *= rc; v.z *= rc; v.w *= rc;
    ((float4*)E)[i] = v;
}

// ---------------------------------------------------------------------------
extern "C" void kernel_launch(void* const* d_in, const int* in_sizes, int n_in,
                              void* d_out, int out_size, void* d_ws, size_t ws_size,
                              hipStream_t stream)
{
    const float* Q = (const float*)d_in[0];
    const float* V = (const float*)d_in[1];
    const int*   M = (const int*)d_in[2];             // bool -> int32 on device

    float* O   = (float*)d_out;                       // [8][2048][128] f32
    float* E   = O + (size_t)NB * TOQ * HD;           // [8][2048][2048] f32
    float* rec = (float*)d_ws;                        // 16384 f32

    k1_scores<<<dim3(TIV / 64, TOQ / 64, NB), 256, 0, stream>>>(Q, V, M, E);
    k2_rowsum<<<dim3(NB * TOQ / 4), 256, 0, stream>>>(E, rec);
    k3_pv   <<<dim3(TOQ / 64, NB), 256, 0, stream>>>(E, V, rec, O);
    k4_norm <<<dim3((int)((size_t)NB * TOQ * TIV / 4 / 256)), 256, 0, stream>>>(E, rec);
}

// Round 4
// 335.856 us; speedup vs baseline: 1.0537x; 1.0537x over previous
//
#include <hip/hip_runtime.h>

#define NB  8
#define TOQ 2048
#define TIV 2048
#define HD  128

typedef float    f32x4  __attribute__((ext_vector_type(4)));
typedef short    s16x8  __attribute__((ext_vector_type(8)));
typedef unsigned short ushort8v __attribute__((ext_vector_type(8)));

__device__ __forceinline__ unsigned short f2bf(float f) {   // RNE f32->bf16
    unsigned u = __float_as_uint(f);
    return (unsigned short)((u + 0x7FFFu + ((u >> 16) & 1u)) >> 16);
}
__device__ __forceinline__ float bf2f(unsigned short h) {
    return __uint_as_float(((unsigned)h) << 16);
}

// split 8 floats into bf16 hi + bf16 lo (lo = x - hi, exact by Sterbenz)
__device__ __forceinline__ void split8(const float4 a, const float4 b,
                                       ushort8v& h, ushort8v& l) {
    const float x[8] = {a.x, a.y, a.z, a.w, b.x, b.y, b.z, b.w};
    #pragma unroll
    for (int j = 0; j < 8; ++j) {
        const unsigned short hi = f2bf(x[j]);
        h[j] = hi;
        l[j] = f2bf(x[j] - bf2f(hi));
    }
}

// ---------------------------------------------------------------------------
// K1: E = mask ? 0 : exp(Q.V^T)  via split-bf16 MFMA (hi*hi + hi*lo + lo*hi)
// 128x128 tile, 4 waves in 2x2, K-chunks of 32 h.
// LDS layout per array: [row 0..127][h 0..31] bf16 row-major (chunk = row*4+kb,
// 16B chunks); fragment read: lane l -> row (l&15), h-chunk (l>>4) -> b128.
// ---------------------------------------------------------------------------
__global__ __launch_bounds__(256) void k1_mfma(
    const float* __restrict__ Q, const float* __restrict__ V,
    const int* __restrict__ M, float* __restrict__ E)
{
    __shared__ unsigned short qhi[128 * 32], qlo[128 * 32];
    __shared__ unsigned short vhi[128 * 32], vlo[128 * 32];

    const int n    = blockIdx.z;
    const int tt   = blockIdx.y * 128;   // to-rows
    const int ts   = blockIdx.x * 128;   // ti-cols
    const int t    = threadIdx.x;
    const int lane = t & 63;
    const int wave = t >> 6;
    const int wr   = wave >> 1;          // 0..1
    const int wc   = wave & 1;           // 0..1
    const int lr   = lane & 15;
    const int kg   = lane >> 4;          // 0..3

    const float* Qb = Q + ((size_t)n * TOQ + tt) * HD;
    const float* Vb = V + ((size_t)n * TIV + ts) * HD;

    f32x4 acc[4][4];
    #pragma unroll
    for (int i = 0; i < 4; ++i)
        #pragma unroll
        for (int j = 0; j < 4; ++j) acc[i][j] = (f32x4)0.f;

    for (int h0 = 0; h0 < HD; h0 += 32) {
        // stage: 512 16B-chunks per array, 2 per thread, coalesced global reads
        #pragma unroll
        for (int it = 0; it < 2; ++it) {
            const int i   = t + it * 256;   // chunk id
            const int row = i >> 2;         // 0..127
            const int kb  = i & 3;          // 8-h chunk
            const float* qs = Qb + (size_t)row * HD + h0 + kb * 8;
            const float* vs = Vb + (size_t)row * HD + h0 + kb * 8;
            const float4 q0 = *(const float4*)qs, q1 = *(const float4*)(qs + 4);
            const float4 v0 = *(const float4*)vs, v1 = *(const float4*)(vs + 4);
            ushort8v qh, ql, vh, vl;
            split8(q0, q1, qh, ql);
            split8(v0, v1, vh, vl);
            *(ushort8v*)(qhi + i * 8) = qh;
            *(ushort8v*)(qlo + i * 8) = ql;
            *(ushort8v*)(vhi + i * 8) = vh;
            *(ushort8v*)(vlo + i * 8) = vl;
        }
        __syncthreads();

        s16x8 aH[4], aL[4];
        #pragma unroll
        for (int fm = 0; fm < 4; ++fm) {
            const int off = (wr * 64 + fm * 16 + lr) * 32 + kg * 8;
            aH[fm] = *(const s16x8*)(qhi + off);
            aL[fm] = *(const s16x8*)(qlo + off);
        }
        #pragma unroll
        for (int fn = 0; fn < 4; ++fn) {
            const int off = (wc * 64 + fn * 16 + lr) * 32 + kg * 8;
            const s16x8 bH = *(const s16x8*)(vhi + off);
            const s16x8 bL = *(const s16x8*)(vlo + off);
            #pragma unroll
            for (int fm = 0; fm < 4; ++fm) {
                acc[fm][fn] = __builtin_amdgcn_mfma_f32_16x16x32_bf16(aH[fm], bH, acc[fm][fn], 0, 0, 0);
                acc[fm][fn] = __builtin_amdgcn_mfma_f32_16x16x32_bf16(aH[fm], bL, acc[fm][fn], 0, 0, 0);
                acc[fm][fn] = __builtin_amdgcn_mfma_f32_16x16x32_bf16(aL[fm], bH, acc[fm][fn], 0, 0, 0);
            }
        }
        __syncthreads();
    }

    // epilogue: mask + exp, scalar but coalesced per 16-lane group
    #pragma unroll
    for (int fm = 0; fm < 4; ++fm) {
        #pragma unroll
        for (int fn = 0; fn < 4; ++fn) {
            #pragma unroll
            for (int ri = 0; ri < 4; ++ri) {
                const int r = tt + wr * 64 + fm * 16 + kg * 4 + ri;  // C/D row
                const int c = ts + wc * 64 + fn * 16 + lr;           // C/D col
                const size_t off = ((size_t)n * TOQ + r) * TIV + c;
                E[off] = M[off] ? 0.f : __expf(acc[fm][fn][ri]);
            }
        }
    }
}

// ---------------------------------------------------------------------------
// K2: rec[row] = 1 / sum_s E[row][s]     (one wave per row)
// ---------------------------------------------------------------------------
__global__ __launch_bounds__(256) void k2_rowsum(
    const float* __restrict__ E, float* __restrict__ rec)
{
    const int row = blockIdx.x * 4 + (threadIdx.x >> 6);
    const int l   = threadIdx.x & 63;
    const float4* Er = (const float4*)(E + (size_t)row * TIV);
    float s = 0.f;
    #pragma unroll
    for (int k = 0; k < 8; ++k) {
        const float4 v = Er[l + 64 * k];
        s += (v.x + v.y) + (v.z + v.w);
    }
    #pragma unroll
    for (int off = 32; off > 0; off >>= 1) s += __shfl_down(s, off, 64);
    if (l == 0) rec[row] = 1.f / s;
}

// ---------------------------------------------------------------------------
// K3': fused normalize + write-back + PV.
// Reads unnormalized E rows, scales by rec at stage time, writes the
// normalized distribution back to E (this IS output P), and accumulates
// O = P.V . K4 eliminated.
// ---------------------------------------------------------------------------
__global__ __launch_bounds__(256) void k3_pv(
    float* __restrict__ E, const float* __restrict__ V,
    const float* __restrict__ rec, float* __restrict__ O)
{
    __shared__ float et[64][68];
    __shared__ float vt[64][132];
    __shared__ float recs[64];

    const int n  = blockIdx.y;
    const int r0 = blockIdx.x * 64;
    const int t  = threadIdx.x;
    const int g  = t >> 5;   // rows 8g..8g+7
    const int c  = t & 31;   // float4 column

    float* Eb = E + ((size_t)n * TOQ + r0) * TIV;
    const float* Vb = V + (size_t)n * TIV * HD;

    if (t < 64) recs[t] = rec[n * TOQ + r0 + t];

    float4 acc[8];
    #pragma unroll
    for (int i = 0; i < 8; ++i) acc[i] = make_float4(0.f, 0.f, 0.f, 0.f);

    for (int s0 = 0; s0 < TIV; s0 += 64) {
        if (s0 == 0) __syncthreads();    // recs visible before first use
        #pragma unroll
        for (int it = 0; it < 4; ++it) {             // stage + normalize + writeback
            const int f = t + it * 256;
            const int row = f >> 4, cg = f & 15;
            float4 e = *(const float4*)&Eb[(size_t)row * TIV + s0 + 4 * cg];
            const float rc = recs[row];
            e.x *= rc; e.y *= rc; e.z *= rc; e.w *= rc;
            *(float4*)&et[row][4 * cg] = e;
            *(float4*)&Eb[(size_t)row * TIV + s0 + 4 * cg] = e;   // P output
        }
        #pragma unroll
        for (int it = 0; it < 8; ++it) {             // stage v 64x128
            const int f = t + it * 256;
            const int sv = f >> 5, hg = f & 31;
            *(float4*)&vt[sv][4 * hg] =
                *(const float4*)&Vb[(size_t)(s0 + sv) * HD + 4 * hg];
        }
        __syncthreads();

        #pragma unroll 2
        for (int s = 0; s < 64; s += 4) {
            const float4 v0 = *(const float4*)&vt[s + 0][4 * c];
            const float4 v1 = *(const float4*)&vt[s + 1][4 * c];
            const float4 v2 = *(const float4*)&vt[s + 2][4 * c];
            const float4 v3 = *(const float4*)&vt[s + 3][4 * c];
            #pragma unroll
            for (int i = 0; i < 8; ++i) {
                const float4 e4 = *(const float4*)&et[8 * g + i][s];
                acc[i].x = fmaf(e4.x, v0.x, fmaf(e4.y, v1.x, fmaf(e4.z, v2.x, fmaf(e4.w, v3.x, acc[i].x))));
                acc[i].y = fmaf(e4.x, v0.y, fmaf(e4.y, v1.y, fmaf(e4.z, v2.y, fmaf(e4.w, v3.y, acc[i].y))));
                acc[i].z = fmaf(e4.x, v0.z, fmaf(e4.y, v1.z, fmaf(e4.z, v2.z, fmaf(e4.w, v3.z, acc[i].z))));
                acc[i].w = fmaf(e4.x, v0.w, fmaf(e4.y, v1.w, fmaf(e4.z, v2.w, fmaf(e4.w, v3.w, acc[i].w))));
            }
        }
        __syncthreads();
    }

    #pragma unroll
    for (int i = 0; i < 8; ++i) {
        const size_t R = (size_t)n * TOQ + r0 + 8 * g + i;
        *(float4*)(O + R * HD + 4 * c) = acc[i];     // already normalized
    }
}

// ---------------------------------------------------------------------------
extern "C" void kernel_launch(void* const* d_in, const int* in_sizes, int n_in,
                              void* d_out, int out_size, void* d_ws, size_t ws_size,
                              hipStream_t stream)
{
    const float* Q = (const float*)d_in[0];
    const float* V = (const float*)d_in[1];
    const int*   M = (const int*)d_in[2];             // bool -> int32 on device

    float* O   = (float*)d_out;                       // [8][2048][128] f32
    float* E   = O + (size_t)NB * TOQ * HD;           // [8][2048][2048] f32
    float* rec = (float*)d_ws;                        // 16384 f32

    k1_mfma  <<<dim3(TIV / 128, TOQ / 128, NB), 256, 0, stream>>>(Q, V, M, E);
    k2_rowsum<<<dim3(NB * TOQ / 4), 256, 0, stream>>>(E, rec);
    k3_pv    <<<dim3(TOQ / 64, NB), 256, 0, stream>>>(E, V, rec, O);
}

// Round 5
// 197.994 us; speedup vs baseline: 1.7874x; 1.6963x over previous
//
#include <hip/hip_runtime.h>

#define NB  8
#define TOQ 2048
#define TIV 2048
#define HD  128

typedef float f32x4 __attribute__((ext_vector_type(4)));
typedef short s16x8 __attribute__((ext_vector_type(8)));
typedef unsigned short ushort8v __attribute__((ext_vector_type(8)));

__device__ __forceinline__ unsigned short f2bf(float f) {   // RNE f32->bf16
    unsigned u = __float_as_uint(f);
    return (unsigned short)((u + 0x7FFFu + ((u >> 16) & 1u)) >> 16);
}
__device__ __forceinline__ float bf2f(unsigned short h) {
    return __uint_as_float(((unsigned)h) << 16);
}

// split 8 floats into bf16 hi + bf16 lo (lo = x - hi)
__device__ __forceinline__ void split8(const float4 a, const float4 b,
                                       ushort8v& h, ushort8v& l) {
    const float x[8] = {a.x, a.y, a.z, a.w, b.x, b.y, b.z, b.w};
    #pragma unroll
    for (int j = 0; j < 8; ++j) {
        const unsigned short hi = f2bf(x[j]);
        h[j] = hi;
        l[j] = f2bf(x[j] - bf2f(hi));
    }
}

// ---------------------------------------------------------------------------
// K0: VT[n][h][s] = bf16(V[n][s][h])  — one-time 4 MB transpose so PV's
// B-fragments are contiguous-k 16B gathers. 64x64 tiles via LDS.
// ---------------------------------------------------------------------------
__global__ __launch_bounds__(256) void k0_vt(
    const float* __restrict__ V, unsigned short* __restrict__ VT)
{
    __shared__ unsigned short tile[64][68];
    const int n  = blockIdx.z;
    const int s0 = blockIdx.x * 64;
    const int h0 = blockIdx.y * 64;
    const int t  = threadIdx.x;

    #pragma unroll
    for (int it = 0; it < 4; ++it) {              // read 64s x 64h coalesced
        const int f = t + it * 256;
        const int r = f >> 4;                     // s index 0..63
        const int c = f & 15;                     // float4 group over h
        const float4 v = *(const float4*)&V[((size_t)(n * TIV + s0 + r)) * HD + h0 + 4 * c];
        tile[4 * c + 0][r] = f2bf(v.x);
        tile[4 * c + 1][r] = f2bf(v.y);
        tile[4 * c + 2][r] = f2bf(v.z);
        tile[4 * c + 3][r] = f2bf(v.w);
    }
    __syncthreads();

    #pragma unroll
    for (int it = 0; it < 2; ++it) {              // write transposed, b128
        const int f  = t + it * 256;
        const int hh = f >> 3;                    // 0..63
        const int sc = f & 7;                     // ushort8 group over s
        ushort8v o;
        #pragma unroll
        for (int j = 0; j < 8; ++j) o[j] = tile[hh][8 * sc + j];
        *(ushort8v*)&VT[((size_t)(n * HD + h0 + hh)) * TIV + s0 + 8 * sc] = o;
    }
}

// ---------------------------------------------------------------------------
// K1: E = mask ? 0 : exp(Q.V^T)  via split-bf16 MFMA  (unchanged, verified)
// ---------------------------------------------------------------------------
__global__ __launch_bounds__(256) void k1_mfma(
    const float* __restrict__ Q, const float* __restrict__ V,
    const int* __restrict__ M, float* __restrict__ E)
{
    __shared__ unsigned short qhi[128 * 32], qlo[128 * 32];
    __shared__ unsigned short vhi[128 * 32], vlo[128 * 32];

    const int n    = blockIdx.z;
    const int tt   = blockIdx.y * 128;
    const int ts   = blockIdx.x * 128;
    const int t    = threadIdx.x;
    const int lane = t & 63;
    const int wave = t >> 6;
    const int wr   = wave >> 1;
    const int wc   = wave & 1;
    const int lr   = lane & 15;
    const int kg   = lane >> 4;

    const float* Qb = Q + ((size_t)n * TOQ + tt) * HD;
    const float* Vb = V + ((size_t)n * TIV + ts) * HD;

    f32x4 acc[4][4];
    #pragma unroll
    for (int i = 0; i < 4; ++i)
        #pragma unroll
        for (int j = 0; j < 4; ++j) acc[i][j] = (f32x4)0.f;

    for (int h0 = 0; h0 < HD; h0 += 32) {
        #pragma unroll
        for (int it = 0; it < 2; ++it) {
            const int i   = t + it * 256;
            const int row = i >> 2;
            const int kb  = i & 3;
            const float* qs = Qb + (size_t)row * HD + h0 + kb * 8;
            const float* vs = Vb + (size_t)row * HD + h0 + kb * 8;
            const float4 q0 = *(const float4*)qs, q1 = *(const float4*)(qs + 4);
            const float4 v0 = *(const float4*)vs, v1 = *(const float4*)(vs + 4);
            ushort8v qh, ql, vh, vl;
            split8(q0, q1, qh, ql);
            split8(v0, v1, vh, vl);
            *(ushort8v*)(qhi + i * 8) = qh;
            *(ushort8v*)(qlo + i * 8) = ql;
            *(ushort8v*)(vhi + i * 8) = vh;
            *(ushort8v*)(vlo + i * 8) = vl;
        }
        __syncthreads();

        s16x8 aH[4], aL[4];
        #pragma unroll
        for (int fm = 0; fm < 4; ++fm) {
            const int off = (wr * 64 + fm * 16 + lr) * 32 + kg * 8;
            aH[fm] = *(const s16x8*)(qhi + off);
            aL[fm] = *(const s16x8*)(qlo + off);
        }
        #pragma unroll
        for (int fn = 0; fn < 4; ++fn) {
            const int off = (wc * 64 + fn * 16 + lr) * 32 + kg * 8;
            const s16x8 bH = *(const s16x8*)(vhi + off);
            const s16x8 bL = *(const s16x8*)(vlo + off);
            #pragma unroll
            for (int fm = 0; fm < 4; ++fm) {
                acc[fm][fn] = __builtin_amdgcn_mfma_f32_16x16x32_bf16(aH[fm], bH, acc[fm][fn], 0, 0, 0);
                acc[fm][fn] = __builtin_amdgcn_mfma_f32_16x16x32_bf16(aH[fm], bL, acc[fm][fn], 0, 0, 0);
                acc[fm][fn] = __builtin_amdgcn_mfma_f32_16x16x32_bf16(aL[fm], bH, acc[fm][fn], 0, 0, 0);
            }
        }
        __syncthreads();
    }

    #pragma unroll
    for (int fm = 0; fm < 4; ++fm) {
        #pragma unroll
        for (int fn = 0; fn < 4; ++fn) {
            #pragma unroll
            for (int ri = 0; ri < 4; ++ri) {
                const int r = tt + wr * 64 + fm * 16 + kg * 4 + ri;
                const int c = ts + wc * 64 + fn * 16 + lr;
                const size_t off = ((size_t)n * TOQ + r) * TIV + c;
                E[off] = M[off] ? 0.f : __expf(acc[fm][fn][ri]);
            }
        }
    }
}

// ---------------------------------------------------------------------------
// K2: rec[row] = 1 / sum_s E[row][s]     (one wave per row)
// ---------------------------------------------------------------------------
__global__ __launch_bounds__(256) void k2_rowsum(
    const float* __restrict__ E, float* __restrict__ rec)
{
    const int row = blockIdx.x * 4 + (threadIdx.x >> 6);
    const int l   = threadIdx.x & 63;
    const float4* Er = (const float4*)(E + (size_t)row * TIV);
    float s = 0.f;
    #pragma unroll
    for (int k = 0; k < 8; ++k) {
        const float4 v = Er[l + 64 * k];
        s += (v.x + v.y) + (v.z + v.w);
    }
    #pragma unroll
    for (int off = 32; off > 0; off >>= 1) s += __shfl_down(s, off, 64);
    if (l == 0) rec[row] = 1.f / s;
}

// ---------------------------------------------------------------------------
// K3: barrier-free fused normalize + P-writeback + MFMA PV.
// 512 threads = 8 waves; wave = (pair p 0..3, half 0..1). Wave owns to-rows
// [r0+16p, r0+16p+16) x k-half [1024*half, +1024). Per k-step 32:
//   A-frag  : lane reads 8 f32 of E at (row = l&15, k + (l>>4)*8)  [HBM stream]
//   P store : same 8 values * rec  written back in f32 (P output)
//   B-frags : 8x 16B gathers from VT (L2-resident)
//   8x mfma_f32_16x16x32_bf16 accumulate O rows in f32.
// Wave pairs reduce their k-halves via LDS at the epilogue. No main-loop
// barriers -> latency hidden by 8 independent waves/CU.
// ---------------------------------------------------------------------------
__global__ __launch_bounds__(512) void k3_pv(
    float* EP,                                   // E in (unnorm) / P out, in place
    const unsigned short* __restrict__ VT,
    const float* __restrict__ rec, float* __restrict__ O)
{
    __shared__ float red[4][16][132];

    const int n    = blockIdx.y;
    const int r0   = blockIdx.x * 64;
    const int t    = threadIdx.x;
    const int wave = t >> 6;
    const int lane = t & 63;
    const int p    = wave >> 1;
    const int half = wave & 1;
    const int lr   = lane & 15;                  // A row / B col / D col
    const int kg   = lane >> 4;                  // k-chunk group

    const int rowg = r0 + p * 16 + lr;           // to-row for A/P/rec
    const float rc = rec[n * TOQ + rowg];
    float* Erow = EP + ((size_t)n * TOQ + rowg) * TIV;
    const unsigned short* VTb = VT + (size_t)n * HD * TIV;

    f32x4 acc[8];
    #pragma unroll
    for (int fn = 0; fn < 8; ++fn) acc[fn] = (f32x4)0.f;

    const int kbase = half * 1024 + kg * 8;

    #pragma unroll 2
    for (int k0 = 0; k0 < 1024; k0 += 32) {
        const int k = kbase + k0;
        const float4 e0 = *(const float4*)&Erow[k];
        const float4 e1 = *(const float4*)&Erow[k + 4];
        float4 p0, p1;
        p0.x = e0.x * rc; p0.y = e0.y * rc; p0.z = e0.z * rc; p0.w = e0.w * rc;
        p1.x = e1.x * rc; p1.y = e1.y * rc; p1.z = e1.z * rc; p1.w = e1.w * rc;
        *(float4*)&Erow[k]     = p0;             // P output (f32)
        *(float4*)&Erow[k + 4] = p1;

        s16x8 a;
        a[0] = (short)f2bf(p0.x); a[1] = (short)f2bf(p0.y);
        a[2] = (short)f2bf(p0.z); a[3] = (short)f2bf(p0.w);
        a[4] = (short)f2bf(p1.x); a[5] = (short)f2bf(p1.y);
        a[6] = (short)f2bf(p1.z); a[7] = (short)f2bf(p1.w);

        #pragma unroll
        for (int fn = 0; fn < 8; ++fn) {
            const s16x8 b = *(const s16x8*)&VTb[(size_t)(fn * 16 + lr) * TIV + k];
            acc[fn] = __builtin_amdgcn_mfma_f32_16x16x32_bf16(a, b, acc[fn], 0, 0, 0);
        }
    }

    // pair reduction: half 1 parks its accumulators in LDS, half 0 adds+stores
    if (half == 1) {
        #pragma unroll
        for (int fn = 0; fn < 8; ++fn)
            #pragma unroll
            for (int ri = 0; ri < 4; ++ri)
                red[p][kg * 4 + ri][fn * 16 + lr] = acc[fn][ri];
    }
    __syncthreads();
    if (half == 0) {
        #pragma unroll
        for (int fn = 0; fn < 8; ++fn) {
            #pragma unroll
            for (int ri = 0; ri < 4; ++ri) {
                const int orow = r0 + p * 16 + kg * 4 + ri;      // D row mapping
                const float o = acc[fn][ri] + red[p][kg * 4 + ri][fn * 16 + lr];
                O[((size_t)n * TOQ + orow) * HD + fn * 16 + lr] = o;
            }
        }
    }
}

// ---------------------------------------------------------------------------
extern "C" void kernel_launch(void* const* d_in, const int* in_sizes, int n_in,
                              void* d_out, int out_size, void* d_ws, size_t ws_size,
                              hipStream_t stream)
{
    const float* Q = (const float*)d_in[0];
    const float* V = (const float*)d_in[1];
    const int*   M = (const int*)d_in[2];

    float* O = (float*)d_out;                         // [8][2048][128] f32
    float* E = O + (size_t)NB * TOQ * HD;             // [8][2048][2048] f32 (P out)

    float*          recb = (float*)d_ws;                              // 64 KB
    unsigned short* VT   = (unsigned short*)((char*)d_ws + (1 << 16)); // 4 MB

    k0_vt    <<<dim3(TIV / 64, HD / 64, NB), 256, 0, stream>>>(V, VT);
    k1_mfma  <<<dim3(TIV / 128, TOQ / 128, NB), 256, 0, stream>>>(Q, V, M, E);
    k2_rowsum<<<dim3(NB * TOQ / 4), 256, 0, stream>>>(E, recb);
    k3_pv    <<<dim3(TOQ / 64, NB), 512, 0, stream>>>(E, VT, recb, O);
}

// Round 6
// 188.019 us; speedup vs baseline: 1.8822x; 1.0530x over previous
//
#include <hip/hip_runtime.h>

#define NB  8
#define TOQ 2048
#define TIV 2048
#define HD  128

typedef float f32x4 __attribute__((ext_vector_type(4)));
typedef short s16x8 __attribute__((ext_vector_type(8)));
typedef unsigned short ushort8v __attribute__((ext_vector_type(8)));

__device__ __forceinline__ unsigned short f2bf(float f) {   // RNE f32->bf16
    unsigned u = __float_as_uint(f);
    return (unsigned short)((u + 0x7FFFu + ((u >> 16) & 1u)) >> 16);
}
__device__ __forceinline__ float bf2f(unsigned short h) {
    return __uint_as_float(((unsigned)h) << 16);
}

__device__ __forceinline__ void split8(const float4 a, const float4 b,
                                       ushort8v& h, ushort8v& l) {
    const float x[8] = {a.x, a.y, a.z, a.w, b.x, b.y, b.z, b.w};
    #pragma unroll
    for (int j = 0; j < 8; ++j) {
        const unsigned short hi = f2bf(x[j]);
        h[j] = hi;
        l[j] = f2bf(x[j] - bf2f(hi));
    }
}

// ---------------------------------------------------------------------------
// K0: VT[n][h][s] = bf16(V[n][s][h])  (4 MB scratch; PV B-frags become 16B
// contiguous-k gathers, L2-resident)
// ---------------------------------------------------------------------------
__global__ __launch_bounds__(256) void k0_vt(
    const float* __restrict__ V, unsigned short* __restrict__ VT)
{
    __shared__ unsigned short tile[64][68];
    const int n  = blockIdx.z;
    const int s0 = blockIdx.x * 64;
    const int h0 = blockIdx.y * 64;
    const int t  = threadIdx.x;

    #pragma unroll
    for (int it = 0; it < 4; ++it) {
        const int f = t + it * 256;
        const int r = f >> 4;
        const int c = f & 15;
        const float4 v = *(const float4*)&V[((size_t)(n * TIV + s0 + r)) * HD + h0 + 4 * c];
        tile[4 * c + 0][r] = f2bf(v.x);
        tile[4 * c + 1][r] = f2bf(v.y);
        tile[4 * c + 2][r] = f2bf(v.z);
        tile[4 * c + 3][r] = f2bf(v.w);
    }
    __syncthreads();

    #pragma unroll
    for (int it = 0; it < 2; ++it) {
        const int f  = t + it * 256;
        const int hh = f >> 3;
        const int sc = f & 7;
        ushort8v o;
        #pragma unroll
        for (int j = 0; j < 8; ++j) o[j] = tile[hh][8 * sc + j];
        *(ushort8v*)&VT[((size_t)(n * HD + h0 + hh)) * TIV + s0 + 8 * sc] = o;
    }
}

// ---------------------------------------------------------------------------
// K1: E = mask ? 0 : exp(Q.V^T) via split-bf16 MFMA + FUSED row partial sums.
// Each block emits, per row it touches, 2 partials (wc=0/1) into
// part[n][row][bx*2+wc]  (32 partials per row total).
// ---------------------------------------------------------------------------
__global__ __launch_bounds__(256) void k1_mfma(
    const float* __restrict__ Q, const float* __restrict__ V,
    const int* __restrict__ M, float* __restrict__ E,
    float* __restrict__ part)
{
    __shared__ unsigned short qhi[128 * 32], qlo[128 * 32];
    __shared__ unsigned short vhi[128 * 32], vlo[128 * 32];

    const int n    = blockIdx.z;
    const int tt   = blockIdx.y * 128;
    const int ts   = blockIdx.x * 128;
    const int t    = threadIdx.x;
    const int lane = t & 63;
    const int wave = t >> 6;
    const int wr   = wave >> 1;
    const int wc   = wave & 1;
    const int lr   = lane & 15;
    const int kg   = lane >> 4;

    const float* Qb = Q + ((size_t)n * TOQ + tt) * HD;
    const float* Vb = V + ((size_t)n * TIV + ts) * HD;

    f32x4 acc[4][4];
    #pragma unroll
    for (int i = 0; i < 4; ++i)
        #pragma unroll
        for (int j = 0; j < 4; ++j) acc[i][j] = (f32x4)0.f;

    for (int h0 = 0; h0 < HD; h0 += 32) {
        #pragma unroll
        for (int it = 0; it < 2; ++it) {
            const int i   = t + it * 256;
            const int row = i >> 2;
            const int kb  = i & 3;
            const float* qs = Qb + (size_t)row * HD + h0 + kb * 8;
            const float* vs = Vb + (size_t)row * HD + h0 + kb * 8;
            const float4 q0 = *(const float4*)qs, q1 = *(const float4*)(qs + 4);
            const float4 v0 = *(const float4*)vs, v1 = *(const float4*)(vs + 4);
            ushort8v qh, ql, vh, vl;
            split8(q0, q1, qh, ql);
            split8(v0, v1, vh, vl);
            *(ushort8v*)(qhi + i * 8) = qh;
            *(ushort8v*)(qlo + i * 8) = ql;
            *(ushort8v*)(vhi + i * 8) = vh;
            *(ushort8v*)(vlo + i * 8) = vl;
        }
        __syncthreads();

        s16x8 aH[4], aL[4];
        #pragma unroll
        for (int fm = 0; fm < 4; ++fm) {
            const int off = (wr * 64 + fm * 16 + lr) * 32 + kg * 8;
            aH[fm] = *(const s16x8*)(qhi + off);
            aL[fm] = *(const s16x8*)(qlo + off);
        }
        #pragma unroll
        for (int fn = 0; fn < 4; ++fn) {
            const int off = (wc * 64 + fn * 16 + lr) * 32 + kg * 8;
            const s16x8 bH = *(const s16x8*)(vhi + off);
            const s16x8 bL = *(const s16x8*)(vlo + off);
            #pragma unroll
            for (int fm = 0; fm < 4; ++fm) {
                acc[fm][fn] = __builtin_amdgcn_mfma_f32_16x16x32_bf16(aH[fm], bH, acc[fm][fn], 0, 0, 0);
                acc[fm][fn] = __builtin_amdgcn_mfma_f32_16x16x32_bf16(aH[fm], bL, acc[fm][fn], 0, 0, 0);
                acc[fm][fn] = __builtin_amdgcn_mfma_f32_16x16x32_bf16(aL[fm], bH, acc[fm][fn], 0, 0, 0);
            }
        }
        __syncthreads();
    }

    // epilogue: mask + exp + store + per-row partial sums
    float rsum[4][4];                      // [fm][ri]
    #pragma unroll
    for (int fm = 0; fm < 4; ++fm)
        #pragma unroll
        for (int ri = 0; ri < 4; ++ri) rsum[fm][ri] = 0.f;

    #pragma unroll
    for (int fm = 0; fm < 4; ++fm) {
        #pragma unroll
        for (int fn = 0; fn < 4; ++fn) {
            #pragma unroll
            for (int ri = 0; ri < 4; ++ri) {
                const int r = tt + wr * 64 + fm * 16 + kg * 4 + ri;
                const int c = ts + wc * 64 + fn * 16 + lr;
                const size_t off = ((size_t)n * TOQ + r) * TIV + c;
                const float e = M[off] ? 0.f : __expf(acc[fm][fn][ri]);
                E[off] = e;
                rsum[fm][ri] += e;
            }
        }
    }
    #pragma unroll
    for (int fm = 0; fm < 4; ++fm) {
        #pragma unroll
        for (int ri = 0; ri < 4; ++ri) {
            float s = rsum[fm][ri];
            s += __shfl_xor(s, 1, 64);
            s += __shfl_xor(s, 2, 64);
            s += __shfl_xor(s, 4, 64);
            s += __shfl_xor(s, 8, 64);
            if (lr == 0) {
                const int r = tt + wr * 64 + fm * 16 + kg * 4 + ri;
                part[((size_t)n * TOQ + r) * 32 + blockIdx.x * 2 + wc] = s;
            }
        }
    }
}

// ---------------------------------------------------------------------------
// K2: rec[row] = 1 / sum of 32 partials   (one thread per row, 2 MB total)
// ---------------------------------------------------------------------------
__global__ __launch_bounds__(256) void k2_rowsum(
    const float* __restrict__ part, float* __restrict__ rec)
{
    const int row = blockIdx.x * 256 + threadIdx.x;
    const float4* p4 = (const float4*)(part + (size_t)row * 32);
    float s = 0.f;
    #pragma unroll
    for (int i = 0; i < 8; ++i) {
        const float4 v = p4[i];
        s += (v.x + v.y) + (v.z + v.w);
    }
    rec[row] = 1.f / s;
}

// ---------------------------------------------------------------------------
// K3: barrier-free fused normalize + P-writeback + MFMA PV.
// 512 blocks x 8 waves: wave = (row-group p 0..1, k-quarter q 0..3).
// Wave owns 16 to-rows x 512 k. 2 blocks/CU -> 16 waves/CU for latency hiding.
// 4-wave LDS reduction per row-group at the epilogue.
// ---------------------------------------------------------------------------
__global__ __launch_bounds__(512) void k3_pv(
    float* __restrict__ EP, const unsigned short* __restrict__ VT,
    const float* __restrict__ rec, float* __restrict__ O)
{
    __shared__ float red[2][3][16][132];

    const int n    = blockIdx.y;
    const int r0   = blockIdx.x * 32;
    const int t    = threadIdx.x;
    const int wave = t >> 6;
    const int lane = t & 63;
    const int p    = wave >> 2;                  // 0..1 row group
    const int q    = wave & 3;                   // 0..3 k quarter
    const int lr   = lane & 15;
    const int kg   = lane >> 4;

    const int rowg = r0 + p * 16 + lr;
    const float rc = rec[n * TOQ + rowg];
    float* Erow = EP + ((size_t)n * TOQ + rowg) * TIV;
    const unsigned short* VTb = VT + (size_t)n * HD * TIV;

    f32x4 acc[8];
    #pragma unroll
    for (int fn = 0; fn < 8; ++fn) acc[fn] = (f32x4)0.f;

    const int kbase = q * 512 + kg * 8;

    #pragma unroll 2
    for (int k0 = 0; k0 < 512; k0 += 32) {
        const int k = kbase + k0;
        const float4 e0 = *(const float4*)&Erow[k];
        const float4 e1 = *(const float4*)&Erow[k + 4];
        float4 p0, p1;
        p0.x = e0.x * rc; p0.y = e0.y * rc; p0.z = e0.z * rc; p0.w = e0.w * rc;
        p1.x = e1.x * rc; p1.y = e1.y * rc; p1.z = e1.z * rc; p1.w = e1.w * rc;
        *(float4*)&Erow[k]     = p0;             // P output (f32)
        *(float4*)&Erow[k + 4] = p1;

        s16x8 a;
        a[0] = (short)f2bf(p0.x); a[1] = (short)f2bf(p0.y);
        a[2] = (short)f2bf(p0.z); a[3] = (short)f2bf(p0.w);
        a[4] = (short)f2bf(p1.x); a[5] = (short)f2bf(p1.y);
        a[6] = (short)f2bf(p1.z); a[7] = (short)f2bf(p1.w);

        #pragma unroll
        for (int fn = 0; fn < 8; ++fn) {
            const s16x8 b = *(const s16x8*)&VTb[(size_t)(fn * 16 + lr) * TIV + k];
            acc[fn] = __builtin_amdgcn_mfma_f32_16x16x32_bf16(a, b, acc[fn], 0, 0, 0);
        }
    }

    // 4-wave reduction per row group: q=1..3 park, q=0 adds + stores
    if (q != 0) {
        #pragma unroll
        for (int fn = 0; fn < 8; ++fn)
            #pragma unroll
            for (int ri = 0; ri < 4; ++ri)
                red[p][q - 1][kg * 4 + ri][fn * 16 + lr] = acc[fn][ri];
    }
    __syncthreads();
    if (q == 0) {
        #pragma unroll
        for (int fn = 0; fn < 8; ++fn) {
            #pragma unroll
            for (int ri = 0; ri < 4; ++ri) {
                const int orow = r0 + p * 16 + kg * 4 + ri;
                float o = acc[fn][ri];
                o += red[p][0][kg * 4 + ri][fn * 16 + lr];
                o += red[p][1][kg * 4 + ri][fn * 16 + lr];
                o += red[p][2][kg * 4 + ri][fn * 16 + lr];
                O[((size_t)n * TOQ + orow) * HD + fn * 16 + lr] = o;
            }
        }
    }
}

// ---------------------------------------------------------------------------
extern "C" void kernel_launch(void* const* d_in, const int* in_sizes, int n_in,
                              void* d_out, int out_size, void* d_ws, size_t ws_size,
                              hipStream_t stream)
{
    const float* Q = (const float*)d_in[0];
    const float* V = (const float*)d_in[1];
    const int*   M = (const int*)d_in[2];

    float* O = (float*)d_out;                         // [8][2048][128] f32
    float* E = O + (size_t)NB * TOQ * HD;             // [8][2048][2048] f32 (P out)

    float*          recb = (float*)d_ws;                                   // 64 KB
    float*          part = (float*)((char*)d_ws + (1 << 16));              // 2 MB
    unsigned short* VT   = (unsigned short*)((char*)d_ws + (1 << 16) + (NB * TOQ * 32 * 4)); // 4 MB

    k0_vt    <<<dim3(TIV / 64, HD / 64, NB), 256, 0, stream>>>(V, VT);
    k1_mfma  <<<dim3(TIV / 128, TOQ / 128, NB), 256, 0, stream>>>(Q, V, M, E, part);
    k2_rowsum<<<dim3(NB * TOQ / 256), 256, 0, stream>>>(part, recb);
    k3_pv    <<<dim3(TOQ / 32, NB), 512, 0, stream>>>(E, VT, recb, O);
}